// Round 6
// baseline (192.823 us; speedup 1.0000x reference)
//
#include <hip/hip_runtime.h>
#include <hip/hip_bf16.h>

typedef float v4f __attribute__((ext_vector_type(4)));
typedef float f32x4 __attribute__((ext_vector_type(4)));
typedef unsigned short u16;
typedef unsigned short us4 __attribute__((ext_vector_type(4)));
typedef unsigned short us8 __attribute__((ext_vector_type(8)));
typedef short s16x8 __attribute__((ext_vector_type(8)));

#define N_NODES 10000
#define N_EDGES 160000

// XOR-swizzle on ushort index: spreads stride-128B rows across bank quads.
#define SWZ(idx, row) ((idx) ^ (((row) & 7) << 3))
// Gather-buffer read index: row r (512B, 64 u16-granules... 32x 16B granules),
// u16 offset o within row; granule XOR'd with row&7 (matches pre-swizzled
// global source in the global_load_lds issue below).
#define GIDX(r, o) (((r) << 8) + (((((o) >> 3) ^ ((r) & 7))) << 3) + ((o) & 7))

__device__ __forceinline__ u16 f2b(float x) {
  union { float f; unsigned u; } v; v.f = x;
  unsigned r = v.u + 0x7fffu + ((v.u >> 16) & 1u);
  return (u16)(r >> 16);
}
__device__ __forceinline__ float b2f(u16 u) {
  union { unsigned u; float f; } v; v.u = ((unsigned)u) << 16; return v.f;
}
__device__ __forceinline__ float silu_f(float x) { return x / (1.0f + __expf(-x)); }

// lgkm-only barrier: keeps global (vmcnt) loads/glds in flight across it.
__device__ __forceinline__ void bar_lgkm() {
  asm volatile("s_waitcnt lgkmcnt(0)" ::: "memory");
  __builtin_amdgcn_s_barrier();
}

// async gather: 16B from per-lane global addr -> LDS base + lane*16
__device__ __forceinline__ void gload_lds16(const u16* g, u16* l) {
  __builtin_amdgcn_global_load_lds(
      (const __attribute__((address_space(1))) unsigned int*)g,
      (__attribute__((address_space(3))) unsigned int*)l, 16, 0, 0);
}

// ---------------- prep: pack weight A-fragments (lane-major, bf16) ----------
// frag f: lane holds A[ut*16 + (lane&15)][kw*32 + (lane>>4)*8 + j], j=0..7.
// Sections (8-ushort frags): L2 @0 (512), L3 @512, L4 @1024 (1024),
// NS @2048 (1024), NV @3072 (1024). Also zeroes charges.
__global__ __launch_bounds__(256) void prep_kernel(
    const float* __restrict__ fcw1, const float* __restrict__ fcw2,
    const float* __restrict__ fcw3,
    const float* __restrict__ W10, const float* __restrict__ W20,
    const float* __restrict__ W11, const float* __restrict__ W21,
    u16* __restrict__ prep, float* __restrict__ charges)
{
  const int fid = blockIdx.x * 256 + threadIdx.x;   // 0..4095
  for (int i = fid; i < N_NODES; i += 4096) charges[i] = 0.f;
  int f, sec;
  if (fid < 512)       { sec = 0; f = fid; }
  else if (fid < 1024) { sec = 1; f = fid - 512; }
  else if (fid < 2048) { sec = 2; f = fid - 1024; }
  else if (fid < 3072) { sec = 3; f = fid - 2048; }
  else                 { sec = 4; f = fid - 3072; }
  const int lane = f & 63, kw = (f >> 6) & 1, ut = f >> 7;
  us8 vals;
  #pragma unroll
  for (int j = 0; j < 8; ++j) {
    const int k = kw * 32 + (lane >> 4) * 8 + j;
    float v;
    if (sec == 0) v = fcw1[k * 64 + ut * 16 + (lane & 15)];
    else if (sec == 1) v = fcw2[k * 64 + ut * 16 + (lane & 15)];
    else if (sec == 2) {
      const int col = (ut < 4) ? (ut * 16 + (lane & 15)) : (192 + (ut - 4) * 16 + (lane & 15));
      v = fcw3[k * 256 + col];
    } else if (sec == 3) {
      const int u = ut * 16 + (lane & 15);
      v = (u < 64) ? W10[k * 64 + u] : W20[k * 64 + (u - 64)];
    } else {
      const int u = ut * 16 + (lane & 15);
      v = (u < 64) ? W11[k * 64 + u] : W21[k * 64 + (u - 64)];
    }
    vals[j] = f2b(v);
  }
  *(us8*)&prep[(size_t)fid * 8] = vals;
}

// ---------------- node kernel: 16 nodes/block, 625 blocks -------------------
// Atab[n][256] = [s1 | v1x | v1y | v1z] bf16 (x0.125 folded); Btab: s2,v2.
__global__ __launch_bounds__(256) void node_kernel(
    const float* __restrict__ nf,
    const u16* __restrict__ prepNS, const u16* __restrict__ prepNV,
    const float* __restrict__ Wm1,
    u16* __restrict__ Atab, u16* __restrict__ Btab, float* __restrict__ out)
{
  __shared__ u16 Ss[1024];
  __shared__ u16 Vs[3][1024];
  const int tid = threadIdx.x, w = tid >> 6, lane = tid & 63;
  const int nb = blockIdx.x;

  #pragma unroll
  for (int it = 0; it < 4; ++it) {
    const int flat = it * 1024 + tid * 4;
    const int nl = flat >> 8;            // 0..15
    const int col = flat & 255;
    const v4f x = *(const v4f*)&nf[((size_t)(nb * 16 + nl)) * 256 + col];
    #pragma unroll
    for (int i = 0; i < 4; ++i) {
      const int c2 = col + i;
      const u16 b = f2b(x[i]);
      if (c2 < 64) Ss[SWZ(nl * 64 + c2, nl)] = b;
      else {
        const int cc = c2 - 64, c = cc / 3, m = cc - c * 3;
        Vs[m][SWZ(nl * 64 + c, nl)] = b;
      }
    }
  }
  __syncthreads();

  const int nr = lane & 15, kg = (lane >> 4) * 8;
  const u16* plane = (w == 0) ? Ss : Vs[w - 1];   // wave = pass (s,x,y,z)
  const u16* pw = (w == 0) ? prepNS : prepNV;
  const s16x8 b0 = *(const s16x8*)&plane[SWZ(nr * 64 + kg, nr)];
  const s16x8 b1 = *(const s16x8*)&plane[SWZ(nr * 64 + 32 + kg, nr)];
  const int node = nb * 16 + nr;
  #pragma unroll
  for (int utg = 0; utg < 8; ++utg) {
    const s16x8 a0 = *(const s16x8*)&pw[((utg * 2 + 0) * 64 + lane) * 8];
    const s16x8 a1 = *(const s16x8*)&pw[((utg * 2 + 1) * 64 + lane) * 8];
    f32x4 acc = {0.f, 0.f, 0.f, 0.f};
    acc = __builtin_amdgcn_mfma_f32_16x16x32_bf16(a0, b0, acc, 0, 0, 0);
    acc = __builtin_amdgcn_mfma_f32_16x16x32_bf16(a1, b1, acc, 0, 0, 0);
    us4 st;
    #pragma unroll
    for (int j = 0; j < 4; ++j) st[j] = f2b(acc[j] * 0.125f);
    u16* tab = (utg < 4) ? Atab : Btab;
    const int ch = w * 64 + (utg & 3) * 16 + (lane >> 4) * 4;
    *(us4*)&tab[(size_t)node * 256 + ch] = st;
  }

  if (tid < 48) {
    const int nl3 = tid / 3, m = tid - nl3 * 3;
    float acc = 0.f;
    #pragma unroll 8
    for (int c = 0; c < 64; ++c)
      acc += b2f(Vs[m][SWZ(nl3 * 64 + c, nl3)]) * Wm1[c];
    out[(nb * 16 + nl3) * 4 + 1 + m] = acc * 0.125f;
  }
}

// layer (32 edges): Hin -> Hout (swizzled [edge][k] bf16), A-frags in VGPRs
__device__ __forceinline__ void mfma_layer32(const u16* Hin, u16* Hout,
                                             s16x8 a0, s16x8 a1, int w, int lane) {
  const int er = lane & 15, kg = (lane >> 4) * 8;
  #pragma unroll
  for (int et = 0; et < 2; ++et) {
    const int e = et * 16 + er;
    const s16x8 b0 = *(const s16x8*)&Hin[SWZ(e * 64 + kg, e)];
    const s16x8 b1 = *(const s16x8*)&Hin[SWZ(e * 64 + 32 + kg, e)];
    f32x4 acc = {0.f, 0.f, 0.f, 0.f};
    acc = __builtin_amdgcn_mfma_f32_16x16x32_bf16(a0, b0, acc, 0, 0, 0);
    acc = __builtin_amdgcn_mfma_f32_16x16x32_bf16(a1, b1, acc, 0, 0, 0);
    us4 st;
    #pragma unroll
    for (int j = 0; j < 4; ++j) st[j] = f2b(silu_f(acc[j] * 0.125f));
    *(us4*)&Hout[SWZ(e * 64 + w * 16 + (lane >> 4) * 4, e)] = st;
  }
}

// ---------------- edge kernel: LDS-prefetched gather + MFMA MLP -------------
// 32 edges/block. G holds 64 table rows (A rows 0..31 = sender of edge e,
// B rows 32..63 = receiver), streamed in via global_load_lds while MLP runs.
__global__ __launch_bounds__(256, 3) void edge_kernel(
    const float* __restrict__ edge_attrs,
    const float* __restrict__ edge_feats,
    const int*   __restrict__ edge_index,
    const float* __restrict__ fcw0,
    const u16*   __restrict__ prep,     // L2 @0, L3 @512*8, L4 @1024*8
    const float* __restrict__ Wf,
    const u16*   __restrict__ Atab, const u16* __restrict__ Btab,
    float* __restrict__ charges, float* __restrict__ p_out)
{
  __shared__ u16 G[16384];             // 32 KB gather buffer
  __shared__ u16 HA[2048], HB[2048];   // activations [e][k], swizzled
  __shared__ float F[256];             // [k][e] 8x32 edge feats
  __shared__ float W0L[512];
  __shared__ float y0L[32], yxL[32], yyL[32], yzL[32];
  __shared__ float Psum[128];          // [wave][edge]

  const int tid = threadIdx.x, w = tid >> 6, lane = tid & 63;
  const int ebase = blockIdx.x * 32;
  const int er = lane & 15, kg = (lane >> 4) * 8;
  const int cb = w * 16 + (lane >> 4) * 4;   // channel base (4 ch)

  // (1) per-edge staging loads; epilogue indices live in tid<32 registers
  int snd0 = 0, rcv0 = 0;
  v4f eaV = {0.f,0.f,0.f,0.f}, f0V = {0.f,0.f,0.f,0.f}, f1V = {0.f,0.f,0.f,0.f};
  if (tid < 32) {
    snd0 = edge_index[ebase + tid];
    rcv0 = edge_index[N_EDGES + ebase + tid];
    eaV = *(const v4f*)&edge_attrs[(size_t)(ebase + tid) * 4];
    f0V = *(const v4f*)&edge_feats[(size_t)(ebase + tid) * 8];
    f1V = *(const v4f*)&edge_feats[(size_t)(ebase + tid) * 8 + 4];
  }
  const float w0a = fcw0[tid], w0b = fcw0[256 + tid];
  // (2) weight fragments (registers, loaded before gathers)
  const u16* pL2 = prep;
  const u16* pL3 = prep + 512 * 8;
  const u16* pL4 = prep + 1024 * 8;
  const s16x8 a2_0 = *(const s16x8*)&pL2[((w * 2 + 0) * 64 + lane) * 8];
  const s16x8 a2_1 = *(const s16x8*)&pL2[((w * 2 + 1) * 64 + lane) * 8];
  const s16x8 a3_0 = *(const s16x8*)&pL3[((w * 2 + 0) * 64 + lane) * 8];
  const s16x8 a3_1 = *(const s16x8*)&pL3[((w * 2 + 1) * 64 + lane) * 8];
  const s16x8 as0 = *(const s16x8*)&pL4[((w * 2 + 0) * 64 + lane) * 8];
  const s16x8 as1 = *(const s16x8*)&pL4[((w * 2 + 1) * 64 + lane) * 8];
  const s16x8 av0 = *(const s16x8*)&pL4[(((4 + w) * 2 + 0) * 64 + lane) * 8];
  const s16x8 av1 = *(const s16x8*)&pL4[(((4 + w) * 2 + 1) * 64 + lane) * 8];
  const v4f wfA = *(const v4f*)&Wf[cb];
  const v4f wfBr = *(const v4f*)&Wf[64 + cb];

  // (3) async gathers: wave w streams G rows 16w..16w+15 (2 rows / inst).
  // Global source granule pre-swizzled by row&7 so swizzled reads are
  // conflict-light while LDS dest stays linear (rule 21).
  {
    const int half = lane >> 5, l31 = lane & 31;
    const u16* tab = (w < 2) ? Atab : Btab;
    const int* eidx = (w < 2) ? (edge_index + ebase) : (edge_index + N_EDGES + ebase);
    #pragma unroll
    for (int i = 0; i < 8; ++i) {
      const int rl = 2 * i + half;                 // row-local 0..15
      const int e = (w & 1) * 16 + rl;             // edge for this row
      const int node = eidx[e];
      const int grow = w * 16 + rl;                // row in G
      const u16* src = tab + (size_t)node * 256 + (size_t)((l31 ^ (grow & 7)) << 3);
      gload_lds16(src, &G[(w * 16 + 2 * i) * 256]);
    }
  }
  __builtin_amdgcn_sched_barrier(0);   // pin gather issue point

  // (4) LDS staging writes
  if (tid < 32) {
    y0L[tid] = eaV[0]; yxL[tid] = eaV[1]; yyL[tid] = eaV[2]; yzL[tid] = eaV[3];
    #pragma unroll
    for (int k = 0; k < 4; ++k) { F[k * 32 + tid] = f0V[k]; F[(k + 4) * 32 + tid] = f1V[k]; }
  }
  W0L[tid] = w0a; W0L[256 + tid] = w0b;
  bar_lgkm();

  // ---- layer 1 (VALU, K=8): lane -> edge lane&31, units w*16+half*8..+7
  {
    const int e = lane & 31, hf = lane >> 5;
    const int u0 = w * 16 + hf * 8;
    float acc[8] = {0.f,0.f,0.f,0.f,0.f,0.f,0.f,0.f};
    #pragma unroll
    for (int k = 0; k < 8; ++k) {
      const float fv = F[k * 32 + e];
      #pragma unroll
      for (int q = 0; q < 2; ++q) {
        const v4f wr = *(const v4f*)&W0L[k * 64 + u0 + q * 4];
        #pragma unroll
        for (int j = 0; j < 4; ++j) acc[q * 4 + j] += fv * wr[j];
      }
    }
    us8 o;
    #pragma unroll
    for (int j = 0; j < 8; ++j) o[j] = f2b(silu_f(acc[j] * 0.35355339059327373f));
    *(us8*)&HA[SWZ(e * 64 + u0, e)] = o;
  }
  bar_lgkm();
  mfma_layer32(HA, HB, a2_0, a2_1, w, lane);   // layer 2
  bar_lgkm();
  mfma_layer32(HB, HA, a3_0, a3_1, w, lane);   // layer 3
  bar_lgkm();

  // ---- layer 4 (MFMA) into registers
  f32x4 accS[2], accV[2];
  #pragma unroll
  for (int et = 0; et < 2; ++et) {
    const int e = et * 16 + er;
    const s16x8 b0 = *(const s16x8*)&HA[SWZ(e * 64 + kg, e)];
    const s16x8 b1 = *(const s16x8*)&HA[SWZ(e * 64 + 32 + kg, e)];
    f32x4 aS = {0.f,0.f,0.f,0.f}, aV = {0.f,0.f,0.f,0.f};
    aS = __builtin_amdgcn_mfma_f32_16x16x32_bf16(as0, b0, aS, 0, 0, 0);
    aS = __builtin_amdgcn_mfma_f32_16x16x32_bf16(as1, b1, aS, 0, 0, 0);
    aV = __builtin_amdgcn_mfma_f32_16x16x32_bf16(av0, b0, aV, 0, 0, 0);
    aV = __builtin_amdgcn_mfma_f32_16x16x32_bf16(av1, b1, aV, 0, 0, 0);
    accS[et] = aS; accV[et] = aV;
  }

  // all gathers landed (each wave waits its own, then barrier syncs all)
  asm volatile("s_waitcnt vmcnt(0)" ::: "memory");
  __builtin_amdgcn_s_barrier();

  // ---- contraction from G
  v4f wfB = wfBr;
  #pragma unroll
  for (int j = 0; j < 4; ++j) wfB[j] *= 0.5773502691896258f;

  #pragma unroll
  for (int et = 0; et < 2; ++et) {
    const int e = et * 16 + er;
    const int rA = e, rB = 32 + e;
    const us4 As = *(const us4*)&G[GIDX(rA, cb)];
    const us4 Ax = *(const us4*)&G[GIDX(rA, 64 + cb)];
    const us4 Ay = *(const us4*)&G[GIDX(rA, 128 + cb)];
    const us4 Az = *(const us4*)&G[GIDX(rA, 192 + cb)];
    const us4 Bs = *(const us4*)&G[GIDX(rB, cb)];
    const us4 Bx = *(const us4*)&G[GIDX(rB, 64 + cb)];
    const us4 By = *(const us4*)&G[GIDX(rB, 128 + cb)];
    const us4 Bz = *(const us4*)&G[GIDX(rB, 192 + cb)];
    const float y0 = y0L[e], yx = yxL[e], yy = yyL[e], yz = yzL[e];
    float part = 0.f;
    #pragma unroll
    for (int j = 0; j < 4; ++j) {
      const float bs = b2f(As[j]) + b2f(Bs[j]);
      const float bv = (b2f(Ax[j]) + b2f(Bx[j])) * yx +
                       (b2f(Ay[j]) + b2f(By[j])) * yy +
                       (b2f(Az[j]) + b2f(Bz[j])) * yz;
      part += accS[et][j] * bs * y0 * wfA[j] + accV[et][j] * bv * wfB[j];
    }
    part += __shfl_xor(part, 16);
    part += __shfl_xor(part, 32);
    if (lane < 16) Psum[w * 32 + et * 16 + lane] = part;
  }
  bar_lgkm();
  if (tid < 32) {
    // fold: 0.125 (layer-4 1/sqrt(64)) / sqrt(128) / 40
    const float p = (Psum[tid] + Psum[32 + tid] + Psum[64 + tid] + Psum[96 + tid])
                    * 2.7621358640766505e-4f;
    p_out[ebase + tid] = p;
    atomicAdd(&charges[rcv0], p);
    atomicAdd(&charges[snd0], -p);
  }
}

// ---------------- finalize ----------------
__global__ void finalize_kernel(const float* __restrict__ charges, float* __restrict__ out) {
  const int n = blockIdx.x * 256 + threadIdx.x;
  if (n < N_NODES) out[n * 4] = charges[n];
}

extern "C" void kernel_launch(void* const* d_in, const int* in_sizes, int n_in,
                              void* d_out, int out_size, void* d_ws, size_t ws_size,
                              hipStream_t stream) {
  const float* node_feats = (const float*)d_in[1];
  const float* edge_attrs = (const float*)d_in[2];
  const float* edge_feats = (const float*)d_in[3];
  const int*   edge_index = (const int*)d_in[4];
  const float* W10  = (const float*)d_in[8];
  const float* W11  = (const float*)d_in[9];
  const float* W20  = (const float*)d_in[10];
  const float* W21  = (const float*)d_in[11];
  const float* fcw0 = (const float*)d_in[12];
  const float* fcw1 = (const float*)d_in[13];
  const float* fcw2 = (const float*)d_in[14];
  const float* fcw3 = (const float*)d_in[15];
  const float* Wf   = (const float*)d_in[16];
  const float* Wm1  = (const float*)d_in[17];
  float* out = (float*)d_out;

  char* ws = (char*)d_ws;
  u16*   Atab    = (u16*)ws;                              // 10000*256 u16
  u16*   Btab    = (u16*)(ws + 5120000);
  float* charges = (float*)(ws + 10240000);
  u16*   prep    = (u16*)(ws + 10280000);                 // 4096 frags * 16B

  prep_kernel<<<16, 256, 0, stream>>>(fcw1, fcw2, fcw3, W10, W20, W11, W21,
                                      prep, charges);
  node_kernel<<<625, 256, 0, stream>>>(node_feats, prep + 2048 * 8, prep + 3072 * 8,
                                       Wm1, Atab, Btab, out);
  edge_kernel<<<5000, 256, 0, stream>>>(edge_attrs, edge_feats, edge_index,
                                        fcw0, prep, Wf, Atab, Btab,
                                        charges, out + 40000);
  finalize_kernel<<<40, 256, 0, stream>>>(charges, out);
}

// Round 7
// 153.147 us; speedup vs baseline: 1.2591x; 1.2591x over previous
//
#include <hip/hip_runtime.h>
#include <hip/hip_bf16.h>

typedef float v4f __attribute__((ext_vector_type(4)));
typedef float f32x4 __attribute__((ext_vector_type(4)));
typedef unsigned short u16;
typedef unsigned short us4 __attribute__((ext_vector_type(4)));
typedef unsigned short us8 __attribute__((ext_vector_type(8)));
typedef short s16x8 __attribute__((ext_vector_type(8)));

#define N_NODES 10000
#define N_EDGES 160000

// XOR-swizzle on ushort index: spreads stride-128B rows across bank quads.
#define SWZ(idx, row) ((idx) ^ (((row) & 7) << 3))
// Gather-buffer read index: row r (512B = 32 x 16B granules), u16 offset o;
// granule XOR'd with row&7 (matches pre-swizzled global source of the glds).
#define GIDX(r, o) (((r) << 8) + (((((o) >> 3) ^ ((r) & 7))) << 3) + ((o) & 7))

__device__ __forceinline__ u16 f2b(float x) {
  union { float f; unsigned u; } v; v.f = x;
  unsigned r = v.u + 0x7fffu + ((v.u >> 16) & 1u);
  return (u16)(r >> 16);
}
__device__ __forceinline__ float b2f(u16 u) {
  union { unsigned u; float f; } v; v.u = ((unsigned)u) << 16; return v.f;
}
__device__ __forceinline__ float silu_f(float x) { return x / (1.0f + __expf(-x)); }

// lgkm-only barrier: keeps global (vmcnt) loads/glds in flight across it.
__device__ __forceinline__ void bar_lgkm() {
  asm volatile("s_waitcnt lgkmcnt(0)" ::: "memory");
  __builtin_amdgcn_s_barrier();
}

// async gather: 16B from per-lane global addr -> LDS base + lane*16
__device__ __forceinline__ void gload_lds16(const u16* g, u16* l) {
  __builtin_amdgcn_global_load_lds(
      (const __attribute__((address_space(1))) unsigned int*)g,
      (__attribute__((address_space(3))) unsigned int*)l, 16, 0, 0);
}

// ---------------- prep: pack weight A-fragments (lane-major, bf16) ----------
// frag f: lane holds A[ut*16 + (lane&15)][kw*32 + (lane>>4)*8 + j], j=0..7.
// Sections (8-ushort frags): L2 @0 (512), L3 @512, L4 @1024 (1024),
// NS @2048 (1024), NV @3072 (1024). Also zeroes the charge slots out[4n].
__global__ __launch_bounds__(256) void prep_kernel(
    const float* __restrict__ fcw1, const float* __restrict__ fcw2,
    const float* __restrict__ fcw3,
    const float* __restrict__ W10, const float* __restrict__ W20,
    const float* __restrict__ W11, const float* __restrict__ W21,
    u16* __restrict__ prep, float* __restrict__ out)
{
  const int fid = blockIdx.x * 256 + threadIdx.x;   // 0..4095
  for (int i = fid; i < N_NODES; i += 4096) out[(size_t)i * 4] = 0.f;
  int f, sec;
  if (fid < 512)       { sec = 0; f = fid; }
  else if (fid < 1024) { sec = 1; f = fid - 512; }
  else if (fid < 2048) { sec = 2; f = fid - 1024; }
  else if (fid < 3072) { sec = 3; f = fid - 2048; }
  else                 { sec = 4; f = fid - 3072; }
  const int lane = f & 63, kw = (f >> 6) & 1, ut = f >> 7;
  us8 vals;
  #pragma unroll
  for (int j = 0; j < 8; ++j) {
    const int k = kw * 32 + (lane >> 4) * 8 + j;
    float v;
    if (sec == 0) v = fcw1[k * 64 + ut * 16 + (lane & 15)];
    else if (sec == 1) v = fcw2[k * 64 + ut * 16 + (lane & 15)];
    else if (sec == 2) {
      const int col = (ut < 4) ? (ut * 16 + (lane & 15)) : (192 + (ut - 4) * 16 + (lane & 15));
      v = fcw3[k * 256 + col];
    } else if (sec == 3) {
      const int u = ut * 16 + (lane & 15);
      v = (u < 64) ? W10[k * 64 + u] : W20[k * 64 + (u - 64)];
    } else {
      const int u = ut * 16 + (lane & 15);
      v = (u < 64) ? W11[k * 64 + u] : W21[k * 64 + (u - 64)];
    }
    vals[j] = f2b(v);
  }
  *(us8*)&prep[(size_t)fid * 8] = vals;
}

// ---------------- node kernel: 16 nodes/block, 625 blocks -------------------
// Atab[n][256] = [s1 | v1x | v1y | v1z] bf16 (x0.125 folded); Btab: s2,v2.
__global__ __launch_bounds__(256) void node_kernel(
    const float* __restrict__ nf,
    const u16* __restrict__ prepNS, const u16* __restrict__ prepNV,
    const float* __restrict__ Wm1,
    u16* __restrict__ Atab, u16* __restrict__ Btab, float* __restrict__ out)
{
  __shared__ u16 Ss[1024];
  __shared__ u16 Vs[3][1024];
  const int tid = threadIdx.x, w = tid >> 6, lane = tid & 63;
  const int nb = blockIdx.x;

  #pragma unroll
  for (int it = 0; it < 4; ++it) {
    const int flat = it * 1024 + tid * 4;
    const int nl = flat >> 8;            // 0..15
    const int col = flat & 255;
    const v4f x = *(const v4f*)&nf[((size_t)(nb * 16 + nl)) * 256 + col];
    #pragma unroll
    for (int i = 0; i < 4; ++i) {
      const int c2 = col + i;
      const u16 b = f2b(x[i]);
      if (c2 < 64) Ss[SWZ(nl * 64 + c2, nl)] = b;
      else {
        const int cc = c2 - 64, c = cc / 3, m = cc - c * 3;
        Vs[m][SWZ(nl * 64 + c, nl)] = b;
      }
    }
  }
  __syncthreads();

  const int nr = lane & 15, kg = (lane >> 4) * 8;
  const u16* plane = (w == 0) ? Ss : Vs[w - 1];   // wave = pass (s,x,y,z)
  const u16* pw = (w == 0) ? prepNS : prepNV;
  const s16x8 b0 = *(const s16x8*)&plane[SWZ(nr * 64 + kg, nr)];
  const s16x8 b1 = *(const s16x8*)&plane[SWZ(nr * 64 + 32 + kg, nr)];
  const int node = nb * 16 + nr;
  #pragma unroll
  for (int utg = 0; utg < 8; ++utg) {
    const s16x8 a0 = *(const s16x8*)&pw[((utg * 2 + 0) * 64 + lane) * 8];
    const s16x8 a1 = *(const s16x8*)&pw[((utg * 2 + 1) * 64 + lane) * 8];
    f32x4 acc = {0.f, 0.f, 0.f, 0.f};
    acc = __builtin_amdgcn_mfma_f32_16x16x32_bf16(a0, b0, acc, 0, 0, 0);
    acc = __builtin_amdgcn_mfma_f32_16x16x32_bf16(a1, b1, acc, 0, 0, 0);
    us4 st;
    #pragma unroll
    for (int j = 0; j < 4; ++j) st[j] = f2b(acc[j] * 0.125f);
    u16* tab = (utg < 4) ? Atab : Btab;
    const int ch = w * 64 + (utg & 3) * 16 + (lane >> 4) * 4;
    *(us4*)&tab[(size_t)node * 256 + ch] = st;
  }

  if (tid < 48) {
    const int nl3 = tid / 3, m = tid - nl3 * 3;
    float acc = 0.f;
    #pragma unroll 8
    for (int c = 0; c < 64; ++c)
      acc += b2f(Vs[m][SWZ(nl3 * 64 + c, nl3)]) * Wm1[c];
    out[(nb * 16 + nl3) * 4 + 1 + m] = acc * 0.125f;
  }
}

// layer (32 edges): Hin -> Hout (swizzled [edge][k] bf16), A-frags in VGPRs
__device__ __forceinline__ void mfma_layer32(const u16* Hin, u16* Hout,
                                             s16x8 a0, s16x8 a1, int w, int lane) {
  const int er = lane & 15, kg = (lane >> 4) * 8;
  #pragma unroll
  for (int et = 0; et < 2; ++et) {
    const int e = et * 16 + er;
    const s16x8 b0 = *(const s16x8*)&Hin[SWZ(e * 64 + kg, e)];
    const s16x8 b1 = *(const s16x8*)&Hin[SWZ(e * 64 + 32 + kg, e)];
    f32x4 acc = {0.f, 0.f, 0.f, 0.f};
    acc = __builtin_amdgcn_mfma_f32_16x16x32_bf16(a0, b0, acc, 0, 0, 0);
    acc = __builtin_amdgcn_mfma_f32_16x16x32_bf16(a1, b1, acc, 0, 0, 0);
    us4 st;
    #pragma unroll
    for (int j = 0; j < 4; ++j) st[j] = f2b(silu_f(acc[j] * 0.125f));
    *(us4*)&Hout[SWZ(e * 64 + w * 16 + (lane >> 4) * 4, e)] = st;
  }
}

// ---------------- edge kernel: 4-tile pipelined blocks ----------------------
// 1250 blocks x 4 tiles of 32 edges. Weights loaded once/block; tile t+1's
// gathers stream into G[nxt] (global_load_lds) while tile t computes.
__global__ __launch_bounds__(256, 2) void edge_kernel(
    const float* __restrict__ edge_attrs,
    const float* __restrict__ edge_feats,
    const int*   __restrict__ edge_index,
    const float* __restrict__ fcw0,
    const u16*   __restrict__ prep,     // L2 @0, L3 @512*8, L4 @1024*8
    const float* __restrict__ Wf,
    const u16*   __restrict__ Atab, const u16* __restrict__ Btab,
    float* __restrict__ out, float* __restrict__ p_out)
{
  __shared__ u16 G[2][16384];          // 2 x 32 KB gather double-buffer
  __shared__ u16 HA[2048], HB[2048];   // activations [e][k], swizzled
  __shared__ float F[256];             // [k][e] 8x32 edge feats
  __shared__ float W0L[512];
  __shared__ float yL[4][32];
  __shared__ float Psum[128];          // [wave][edge]

  const int tid = threadIdx.x, w = tid >> 6, lane = tid & 63;
  const int half = lane >> 5, l31 = lane & 31;
  const int er = lane & 15, kg = (lane >> 4) * 8;
  const int cb = w * 16 + (lane >> 4) * 4;   // channel base (4 ch)
  const int eb0 = blockIdx.x * 128;          // 4 tiles x 32 edges

  // ---- persistent weights (once per block) ----
  const u16* pL2 = prep;
  const u16* pL3 = prep + 512 * 8;
  const u16* pL4 = prep + 1024 * 8;
  const s16x8 a2_0 = *(const s16x8*)&pL2[((w * 2 + 0) * 64 + lane) * 8];
  const s16x8 a2_1 = *(const s16x8*)&pL2[((w * 2 + 1) * 64 + lane) * 8];
  const s16x8 a3_0 = *(const s16x8*)&pL3[((w * 2 + 0) * 64 + lane) * 8];
  const s16x8 a3_1 = *(const s16x8*)&pL3[((w * 2 + 1) * 64 + lane) * 8];
  const s16x8 as0 = *(const s16x8*)&pL4[((w * 2 + 0) * 64 + lane) * 8];
  const s16x8 as1 = *(const s16x8*)&pL4[((w * 2 + 1) * 64 + lane) * 8];
  const s16x8 av0 = *(const s16x8*)&pL4[(((4 + w) * 2 + 0) * 64 + lane) * 8];
  const s16x8 av1 = *(const s16x8*)&pL4[(((4 + w) * 2 + 1) * 64 + lane) * 8];
  const v4f wfA = *(const v4f*)&Wf[cb];
  v4f wfB = *(const v4f*)&Wf[64 + cb];
  #pragma unroll
  for (int j = 0; j < 4; ++j) wfB[j] *= 0.5773502691896258f;
  W0L[tid] = fcw0[tid]; W0L[256 + tid] = fcw0[256 + tid];

  const u16* tabW = (w < 2) ? Atab : Btab;          // this wave gathers A or B
  const int  eoff = (w < 2) ? 0 : N_EDGES;

  // cross-tile register state (all indices static under full unroll)
  int nidx[2][8];
  int sndR[2], rcvR[2];
  v4f eaR[2], f0R[2], f1R[2];

  // ---- prologue: tile 0 ----
  {
    #pragma unroll
    for (int i = 0; i < 8; ++i)
      nidx[0][i] = edge_index[eoff + eb0 + (w & 1) * 16 + 2 * i + half];
    if (tid < 32) {
      sndR[0] = edge_index[eb0 + tid];
      rcvR[0] = edge_index[N_EDGES + eb0 + tid];
      eaR[0] = *(const v4f*)&edge_attrs[(size_t)(eb0 + tid) * 4];
      f0R[0] = *(const v4f*)&edge_feats[(size_t)(eb0 + tid) * 8];
      f1R[0] = *(const v4f*)&edge_feats[(size_t)(eb0 + tid) * 8 + 4];
    }
    asm volatile("s_waitcnt vmcnt(0)" ::: "memory");
    #pragma unroll
    for (int i = 0; i < 8; ++i) {
      const int grow = w * 16 + 2 * i + half;
      const u16* src = tabW + (size_t)nidx[0][i] * 256 + (size_t)((l31 ^ (grow & 7)) << 3);
      gload_lds16(src, &G[0][(w * 16 + 2 * i) * 256]);
    }
    __builtin_amdgcn_sched_barrier(0);
    if (tid < 32) {
      yL[0][tid] = eaR[0][0]; yL[1][tid] = eaR[0][1];
      yL[2][tid] = eaR[0][2]; yL[3][tid] = eaR[0][3];
      #pragma unroll
      for (int k = 0; k < 4; ++k) {
        F[k * 32 + tid] = f0R[0][k]; F[(k + 4) * 32 + tid] = f1R[0][k];
      }
    }
    bar_lgkm();
  }

  #pragma unroll
  for (int t = 0; t < 4; ++t) {
    const int cur = t & 1, nxt = cur ^ 1;
    const int eb = eb0 + t * 32;

    // (1) issue next tile's index + staging loads (land during this MLP)
    if (t < 3) {
      const int ebn = eb + 32;
      #pragma unroll
      for (int i = 0; i < 8; ++i)
        nidx[nxt][i] = edge_index[eoff + ebn + (w & 1) * 16 + 2 * i + half];
      if (tid < 32) {
        sndR[nxt] = edge_index[ebn + tid];
        rcvR[nxt] = edge_index[N_EDGES + ebn + tid];
        eaR[nxt] = *(const v4f*)&edge_attrs[(size_t)(ebn + tid) * 4];
        f0R[nxt] = *(const v4f*)&edge_feats[(size_t)(ebn + tid) * 8];
        f1R[nxt] = *(const v4f*)&edge_feats[(size_t)(ebn + tid) * 8 + 4];
      }
      __builtin_amdgcn_sched_barrier(0);   // pin issue point
    }

    // (2) layer 1 (VALU, K=8): lane -> edge l31, units w*16+half*8..+7
    {
      const int u0 = w * 16 + half * 8;
      float acc[8] = {0.f,0.f,0.f,0.f,0.f,0.f,0.f,0.f};
      #pragma unroll
      for (int k = 0; k < 8; ++k) {
        const float fv = F[k * 32 + l31];
        #pragma unroll
        for (int q = 0; q < 2; ++q) {
          const v4f wr = *(const v4f*)&W0L[k * 64 + u0 + q * 4];
          #pragma unroll
          for (int j = 0; j < 4; ++j) acc[q * 4 + j] += fv * wr[j];
        }
      }
      us8 o;
      #pragma unroll
      for (int j = 0; j < 8; ++j) o[j] = f2b(silu_f(acc[j] * 0.35355339059327373f));
      *(us8*)&HA[SWZ(l31 * 64 + u0, l31)] = o;
    }
    bar_lgkm();
    mfma_layer32(HA, HB, a2_0, a2_1, w, lane);   // layer 2
    bar_lgkm();
    mfma_layer32(HB, HA, a3_0, a3_1, w, lane);   // layer 3
    bar_lgkm();

    // (5) layer 4 (MFMA) into registers
    f32x4 accS[2], accV[2];
    #pragma unroll
    for (int et = 0; et < 2; ++et) {
      const int e = et * 16 + er;
      const s16x8 b0 = *(const s16x8*)&HA[SWZ(e * 64 + kg, e)];
      const s16x8 b1 = *(const s16x8*)&HA[SWZ(e * 64 + 32 + kg, e)];
      f32x4 aS = {0.f,0.f,0.f,0.f}, aV = {0.f,0.f,0.f,0.f};
      aS = __builtin_amdgcn_mfma_f32_16x16x32_bf16(as0, b0, aS, 0, 0, 0);
      aS = __builtin_amdgcn_mfma_f32_16x16x32_bf16(as1, b1, aS, 0, 0, 0);
      aV = __builtin_amdgcn_mfma_f32_16x16x32_bf16(av0, b0, aV, 0, 0, 0);
      aV = __builtin_amdgcn_mfma_f32_16x16x32_bf16(av1, b1, aV, 0, 0, 0);
      accS[et] = aS; accV[et] = aV;
    }

    // (6) own gathers(t) + idx(t+1) landed
    asm volatile("s_waitcnt vmcnt(0)" ::: "memory");
    // (7) issue gathers(t+1) into the other buffer (in flight across barrier)
    if (t < 3) {
      #pragma unroll
      for (int i = 0; i < 8; ++i) {
        const int grow = w * 16 + 2 * i + half;
        const u16* src = tabW + (size_t)nidx[nxt][i] * 256 + (size_t)((l31 ^ (grow & 7)) << 3);
        gload_lds16(src, &G[nxt][(w * 16 + 2 * i) * 256]);
      }
      __builtin_amdgcn_sched_barrier(0);
    }
    __builtin_amdgcn_s_barrier();        // all waves' G[cur] rows visible

    // (9) contraction from G[cur]
    #pragma unroll
    for (int et = 0; et < 2; ++et) {
      const int e = et * 16 + er;
      const int rA = e, rB = 32 + e;
      const us4 As = *(const us4*)&G[cur][GIDX(rA, cb)];
      const us4 Ax = *(const us4*)&G[cur][GIDX(rA, 64 + cb)];
      const us4 Ay = *(const us4*)&G[cur][GIDX(rA, 128 + cb)];
      const us4 Az = *(const us4*)&G[cur][GIDX(rA, 192 + cb)];
      const us4 Bs = *(const us4*)&G[cur][GIDX(rB, cb)];
      const us4 Bx = *(const us4*)&G[cur][GIDX(rB, 64 + cb)];
      const us4 By = *(const us4*)&G[cur][GIDX(rB, 128 + cb)];
      const us4 Bz = *(const us4*)&G[cur][GIDX(rB, 192 + cb)];
      const float y0 = yL[0][e], yx = yL[1][e], yy = yL[2][e], yz = yL[3][e];
      float part = 0.f;
      #pragma unroll
      for (int j = 0; j < 4; ++j) {
        const float bs = b2f(As[j]) + b2f(Bs[j]);
        const float bv = (b2f(Ax[j]) + b2f(Bx[j])) * yx +
                         (b2f(Ay[j]) + b2f(By[j])) * yy +
                         (b2f(Az[j]) + b2f(Bz[j])) * yz;
        part += accS[et][j] * bs * y0 * wfA[j] + accV[et][j] * bv * wfB[j];
      }
      part += __shfl_xor(part, 16);
      part += __shfl_xor(part, 32);
      if (lane < 16) Psum[w * 32 + et * 16 + lane] = part;
    }
    bar_lgkm();
    if (tid < 32) {
      // fold: 0.125 (layer-4 1/sqrt(64)) / sqrt(128) / 40
      const float p = (Psum[tid] + Psum[32 + tid] + Psum[64 + tid] + Psum[96 + tid])
                      * 2.7621358640766505e-4f;
      p_out[eb + tid] = p;
      atomicAdd(&out[(size_t)rcvR[cur] * 4], p);
      atomicAdd(&out[(size_t)sndR[cur] * 4], -p);
      if (t < 3) {    // stage next tile's F / y (after y(t) fully consumed)
        yL[0][tid] = eaR[nxt][0]; yL[1][tid] = eaR[nxt][1];
        yL[2][tid] = eaR[nxt][2]; yL[3][tid] = eaR[nxt][3];
        #pragma unroll
        for (int k = 0; k < 4; ++k) {
          F[k * 32 + tid] = f0R[nxt][k]; F[(k + 4) * 32 + tid] = f1R[nxt][k];
        }
      }
    }
    bar_lgkm();
  }
}

extern "C" void kernel_launch(void* const* d_in, const int* in_sizes, int n_in,
                              void* d_out, int out_size, void* d_ws, size_t ws_size,
                              hipStream_t stream) {
  const float* node_feats = (const float*)d_in[1];
  const float* edge_attrs = (const float*)d_in[2];
  const float* edge_feats = (const float*)d_in[3];
  const int*   edge_index = (const int*)d_in[4];
  const float* W10  = (const float*)d_in[8];
  const float* W11  = (const float*)d_in[9];
  const float* W20  = (const float*)d_in[10];
  const float* W21  = (const float*)d_in[11];
  const float* fcw0 = (const float*)d_in[12];
  const float* fcw1 = (const float*)d_in[13];
  const float* fcw2 = (const float*)d_in[14];
  const float* fcw3 = (const float*)d_in[15];
  const float* Wf   = (const float*)d_in[16];
  const float* Wm1  = (const float*)d_in[17];
  float* out = (float*)d_out;

  char* ws = (char*)d_ws;
  u16* Atab = (u16*)ws;                              // 10000*256 u16
  u16* Btab = (u16*)(ws + 5120000);
  u16* prep = (u16*)(ws + 10240000);                 // 4096 frags * 16B

  prep_kernel<<<16, 256, 0, stream>>>(fcw1, fcw2, fcw3, W10, W20, W11, W21,
                                      prep, out);
  node_kernel<<<625, 256, 0, stream>>>(node_feats, prep + 2048 * 8, prep + 3072 * 8,
                                       Wm1, Atab, Btab, out);
  edge_kernel<<<1250, 256, 0, stream>>>(edge_attrs, edge_feats, edge_index,
                                        fcw0, prep, Wf, Atab, Btab,
                                        out, out + 40000);
}